// Round 9
// baseline (98.134 us; speedup 1.0000x reference)
//
#include <hip/hip_runtime.h>
#include <math.h>

#define CC    144
#define WW    9225
#define KWW   10
#define FF    64
#define H1N   128
#define CONVN (WW - KWW + 1)   // 9216
#define CFN   (CC * FF)        // 9216
#define CATN  (CFN + CONVN)    // 18432
#define FCB2  (CC * 8)         // 1152 fc blocks: (channel c, f-group g of 8)
#define NFULL 144              // 144*64 = 9216 full-lane iterations
#define NTAIL 9                // 9225 - 9216

typedef float f32x4 __attribute__((ext_vector_type(4)));

// ---------------------------------------------------------------------------
// Stage 1 v7: v6 structure (x row staged in LDS; each wave streams two
// contiguous Wfc rows with scalar lane-consecutive loads) + PER-ROW PHASE
// ROTATION: wave starts its k-loop at k0=(row*59)%144 and wraps. Goal:
// decorrelate the ~9216 lockstep streams whose constant 36.9KB spacing maps
// to a narrow set of HBM channels at any instant (theory for the 4.3 TB/s cap).
//   blocks [0, FCB2): fc.  blocks [FCB2, FCB2+36): conv (256 positions each).
// ---------------------------------------------------------------------------
__global__ __launch_bounds__(256) void k_front_v7(
    const float* __restrict__ x,     // [C, W]
    const float* __restrict__ Wfc,   // [C, F, W]
    const float* __restrict__ bfc,   // [C, F]
    const float* __restrict__ Kc,    // [C, KW]
    const float* __restrict__ bconv, // [1]
    float* __restrict__ concat)      // [CATN]
{
    __shared__ float smem[WW];       // 36.9 KB; conv blocks use first 1440
    const int bid = blockIdx.x;
    const int tid = threadIdx.x;

    if (bid < FCB2) {
        const int c = bid >> 3;                   // channel
        const int g = bid & 7;                    // f-group
        const float* __restrict__ xr = x + (size_t)c * WW;

        // ---- stage x row into LDS (coalesced)
        for (int i = tid; i < WW; i += 256) smem[i] = xr[i];
        __syncthreads();

        // ---- each wave: rows r0, r0+1
        const int wave = tid >> 6;
        const int lane = tid & 63;
        const int f0   = g * 8 + wave * 2;
        const int r0   = (c << 6) + f0;           // fc row index
        const float* __restrict__ w0 = Wfc + (size_t)r0 * WW + lane;
        const float* __restrict__ w1 = w0 + WW;

        // per-row phase rotation
        const int k0 = (r0 * 59) % NFULL;

        float a0 = 0.f, a1 = 0.f;
        #pragma unroll 4
        for (int k = k0; k < NFULL; ++k) {
            const int idx = (k << 6);
            const float xv = smem[idx + lane];
            a0 = fmaf(w0[idx], xv, a0);
            a1 = fmaf(w1[idx], xv, a1);
        }
        #pragma unroll 4
        for (int k = 0; k < k0; ++k) {
            const int idx = (k << 6);
            const float xv = smem[idx + lane];
            a0 = fmaf(w0[idx], xv, a0);
            a1 = fmaf(w1[idx], xv, a1);
        }
        // tail: elements 9216..9224 (explicit, base pointers without +lane)
        if (lane < NTAIL) {
            const int e = NFULL * 64 + lane;
            const float xv = smem[e];
            const float* __restrict__ wb0 = Wfc + (size_t)r0 * WW;
            a0 = fmaf(wb0[e],      xv, a0);
            a1 = fmaf(wb0[WW + e], xv, a1);
        }

        // wave-only reduction
        #pragma unroll
        for (int off = 32; off > 0; off >>= 1) {
            a0 += __shfl_xor(a0, off, 64);
            a1 += __shfl_xor(a1, off, 64);
        }
        if (lane == 0) {
            concat[r0]     = a0 + bfc[r0];
            concat[r0 + 1] = a1 + bfc[r0 + 1];
        }
    } else {
        // ---- conv: position p = (bid-FCB2)*256 + tid
        for (int i = tid; i < CC * KWW; i += 256) smem[i] = Kc[i];
        __syncthreads();

        const int p = (bid - FCB2) * 256 + tid;   // 36*256 == 9216 exactly
        float acc = bconv[0];
        for (int c = 0; c < CC; ++c) {
            const float* __restrict__ xr = x + (size_t)c * WW + p;
            const float* __restrict__ kr = smem + c * KWW;
            #pragma unroll
            for (int k = 0; k < KWW; ++k)
                acc = fmaf(xr[k], kr[k], acc);
        }
        concat[CFN + p] = acc;
    }
}

// ---------------------------------------------------------------------------
// Stage 2: 256 blocks; block j = (h = j>>1, half = j&1) half-row partial dot.
// ---------------------------------------------------------------------------
__global__ __launch_bounds__(256) void k_layer1_v2(
    const float* __restrict__ W1,     // [H1, CAT]
    const float* __restrict__ concat, // [CAT]
    float* __restrict__ partial)      // [256]
{
    __shared__ float sm[4];
    const int j = blockIdx.x, tid = threadIdx.x;
    const int h = j >> 1, half = j & 1;
    const f32x4* __restrict__ wr =
        (const f32x4*)(W1 + (size_t)h * CATN + half * (CATN / 2));
    const f32x4* __restrict__ cv =
        (const f32x4*)(concat + half * (CATN / 2));

    float acc = 0.f;
    for (int i = tid; i < CATN / 8; i += 256) {   // 9 iters
        const f32x4 a = wr[i];
        const f32x4 q = cv[i];
        acc += a.x * q.x + a.y * q.y + a.z * q.z + a.w * q.w;
    }
    #pragma unroll
    for (int off = 32; off > 0; off >>= 1)
        acc += __shfl_xor(acc, off, 64);
    if ((tid & 63) == 0) sm[tid >> 6] = acc;
    __syncthreads();
    if (tid == 0)
        partial[j] = sm[0] + sm[1] + sm[2] + sm[3];
}

// ---------------------------------------------------------------------------
// Stage 3: combine partials + bias + relu, dot with W2, relu, sigmoid.
// ---------------------------------------------------------------------------
__global__ __launch_bounds__(128) void k_final_v2(
    const float* __restrict__ partial, // [256]
    const float* __restrict__ b1,      // [H1]
    const float* __restrict__ W2,      // [1, H1]
    const float* __restrict__ b2,      // [1]
    float* __restrict__ out)           // [1]
{
    __shared__ float sm[2];
    const int tid = threadIdx.x;
    float v = fmaxf(partial[2 * tid] + partial[2 * tid + 1] + b1[tid], 0.f)
              * W2[tid];
    #pragma unroll
    for (int off = 32; off > 0; off >>= 1)
        v += __shfl_xor(v, off, 64);
    if ((tid & 63) == 0) sm[tid >> 6] = v;
    __syncthreads();
    if (tid == 0) {
        float z = sm[0] + sm[1] + b2[0];
        z = fmaxf(z, 0.f);
        out[0] = 1.f / (1.f + expf(-z));
    }
}

extern "C" void kernel_launch(void* const* d_in, const int* in_sizes, int n_in,
                              void* d_out, int out_size, void* d_ws, size_t ws_size,
                              hipStream_t stream) {
    const float* x     = (const float*)d_in[0];
    const float* Wfc   = (const float*)d_in[1];
    const float* bfc   = (const float*)d_in[2];
    const float* Kc    = (const float*)d_in[3];
    const float* bconv = (const float*)d_in[4];
    const float* W1    = (const float*)d_in[5];
    const float* b1    = (const float*)d_in[6];
    const float* W2    = (const float*)d_in[7];
    const float* b2    = (const float*)d_in[8];
    float* out = (float*)d_out;

    float* concat  = (float*)d_ws;         // [CATN]
    float* partial = concat + CATN;        // [256]

    k_front_v7 <<<FCB2 + (CONVN / 256), 256, 0, stream>>>(
        x, Wfc, bfc, Kc, bconv, concat);
    k_layer1_v2<<<256, 256, 0, stream>>>(W1, concat, partial);
    k_final_v2 <<<1, 128, 0, stream>>>(partial, b1, W2, b2, out);
}

// Round 10
// 80.216 us; speedup vs baseline: 1.2234x; 1.2234x over previous
//
#include <hip/hip_runtime.h>
#include <math.h>

#define CC    144
#define WW    9225
#define KWW   10
#define FF    64
#define H1N   128
#define CONVN (WW - KWW + 1)   // 9216
#define CFN   (CC * FF)        // 9216
#define CATN  (CFN + CONVN)    // 18432
#define FCB2  (CC * 8)         // 1152 fc blocks: (channel c, f-group g of 8)
#define NFULL 144              // 144*64 = 9216 full-lane iterations
#define NTAIL 9                // 9225 - 9216
#define HOTC  96               // channels < HOTC: normal loads (L3-resident
                               // slice, 96*64*36900B = 226.7 MB + x + W1 < 256MB
                               // L3); channels >= HOTC: nontemporal (no L3
                               // alloc) so the hot slice survives replays.

typedef float f32x4 __attribute__((ext_vector_type(4)));

// ---------------------------------------------------------------------------
// Stage 1 v8 = v6 structure (x row in LDS; each wave streams two contiguous
// Wfc rows, scalar lane-consecutive loads; no phase rotation) + L3 residency
// split: cold slice (c>=HOTC) read nontemporally so the hot slice stays in
// Infinity Cache across graph replays, cutting effective read latency (MSHR-
// limited BW theory: BW = inflight_bytes / latency).
//   blocks [0, FCB2): fc.  blocks [FCB2, FCB2+36): conv (256 positions each).
// ---------------------------------------------------------------------------
__global__ __launch_bounds__(256) void k_front_v8(
    const float* __restrict__ x,     // [C, W]
    const float* __restrict__ Wfc,   // [C, F, W]
    const float* __restrict__ bfc,   // [C, F]
    const float* __restrict__ Kc,    // [C, KW]
    const float* __restrict__ bconv, // [1]
    float* __restrict__ concat)      // [CATN]
{
    __shared__ float smem[WW];       // 36.9 KB; conv blocks use first 1440
    const int bid = blockIdx.x;
    const int tid = threadIdx.x;

    if (bid < FCB2) {
        const int c = bid >> 3;                   // channel
        const int g = bid & 7;                    // f-group
        const float* __restrict__ xr = x + (size_t)c * WW;

        // ---- stage x row into LDS (coalesced)
        for (int i = tid; i < WW; i += 256) smem[i] = xr[i];
        __syncthreads();

        // ---- each wave: rows r0, r0+1
        const int wave = tid >> 6;
        const int lane = tid & 63;
        const int f0   = g * 8 + wave * 2;
        const int r0   = (c << 6) + f0;           // fc row index
        const float* __restrict__ w0 = Wfc + (size_t)r0 * WW + lane;
        const float* __restrict__ w1 = w0 + WW;

        float a0 = 0.f, a1 = 0.f;
        if (c < HOTC) {
            // hot slice: normal loads -> allocate in L3, survive replays
            #pragma unroll 8
            for (int k = 0; k < NFULL; ++k) {
                const int idx = (k << 6);
                const float xv = smem[idx + lane];
                a0 = fmaf(w0[idx], xv, a0);
                a1 = fmaf(w1[idx], xv, a1);
            }
        } else {
            // cold slice: nontemporal -> don't evict the hot slice
            #pragma unroll 8
            for (int k = 0; k < NFULL; ++k) {
                const int idx = (k << 6);
                const float xv = smem[idx + lane];
                a0 = fmaf(__builtin_nontemporal_load(w0 + idx), xv, a0);
                a1 = fmaf(__builtin_nontemporal_load(w1 + idx), xv, a1);
            }
        }
        // tail: elements 9216..9224 (explicit base pointers, no +lane bias)
        if (lane < NTAIL) {
            const int e = NFULL * 64 + lane;
            const float xv = smem[e];
            const float* __restrict__ wb0 = Wfc + (size_t)r0 * WW;
            a0 = fmaf(wb0[e],      xv, a0);
            a1 = fmaf(wb0[WW + e], xv, a1);
        }

        // wave-only reduction — no LDS, no __syncthreads
        #pragma unroll
        for (int off = 32; off > 0; off >>= 1) {
            a0 += __shfl_xor(a0, off, 64);
            a1 += __shfl_xor(a1, off, 64);
        }
        if (lane == 0) {
            concat[r0]     = a0 + bfc[r0];
            concat[r0 + 1] = a1 + bfc[r0 + 1];
        }
    } else {
        // ---- conv: position p = (bid-FCB2)*256 + tid
        for (int i = tid; i < CC * KWW; i += 256) smem[i] = Kc[i];
        __syncthreads();

        const int p = (bid - FCB2) * 256 + tid;   // 36*256 == 9216 exactly
        float acc = bconv[0];
        for (int c = 0; c < CC; ++c) {
            const float* __restrict__ xr = x + (size_t)c * WW + p;
            const float* __restrict__ kr = smem + c * KWW;
            #pragma unroll
            for (int k = 0; k < KWW; ++k)
                acc = fmaf(xr[k], kr[k], acc);
        }
        concat[CFN + p] = acc;
    }
}

// ---------------------------------------------------------------------------
// Stage 2: 256 blocks; block j = (h = j>>1, half = j&1) half-row partial dot.
// ---------------------------------------------------------------------------
__global__ __launch_bounds__(256) void k_layer1_v2(
    const float* __restrict__ W1,     // [H1, CAT]
    const float* __restrict__ concat, // [CAT]
    float* __restrict__ partial)      // [256]
{
    __shared__ float sm[4];
    const int j = blockIdx.x, tid = threadIdx.x;
    const int h = j >> 1, half = j & 1;
    const f32x4* __restrict__ wr =
        (const f32x4*)(W1 + (size_t)h * CATN + half * (CATN / 2));
    const f32x4* __restrict__ cv =
        (const f32x4*)(concat + half * (CATN / 2));

    float acc = 0.f;
    for (int i = tid; i < CATN / 8; i += 256) {   // 9 iters
        const f32x4 a = wr[i];
        const f32x4 q = cv[i];
        acc += a.x * q.x + a.y * q.y + a.z * q.z + a.w * q.w;
    }
    #pragma unroll
    for (int off = 32; off > 0; off >>= 1)
        acc += __shfl_xor(acc, off, 64);
    if ((tid & 63) == 0) sm[tid >> 6] = acc;
    __syncthreads();
    if (tid == 0)
        partial[j] = sm[0] + sm[1] + sm[2] + sm[3];
}

// ---------------------------------------------------------------------------
// Stage 3: combine partials + bias + relu, dot with W2, relu, sigmoid.
// ---------------------------------------------------------------------------
__global__ __launch_bounds__(128) void k_final_v2(
    const float* __restrict__ partial, // [256]
    const float* __restrict__ b1,      // [H1]
    const float* __restrict__ W2,      // [1, H1]
    const float* __restrict__ b2,      // [1]
    float* __restrict__ out)           // [1]
{
    __shared__ float sm[2];
    const int tid = threadIdx.x;
    float v = fmaxf(partial[2 * tid] + partial[2 * tid + 1] + b1[tid], 0.f)
              * W2[tid];
    #pragma unroll
    for (int off = 32; off > 0; off >>= 1)
        v += __shfl_xor(v, off, 64);
    if ((tid & 63) == 0) sm[tid >> 6] = v;
    __syncthreads();
    if (tid == 0) {
        float z = sm[0] + sm[1] + b2[0];
        z = fmaxf(z, 0.f);
        out[0] = 1.f / (1.f + expf(-z));
    }
}

extern "C" void kernel_launch(void* const* d_in, const int* in_sizes, int n_in,
                              void* d_out, int out_size, void* d_ws, size_t ws_size,
                              hipStream_t stream) {
    const float* x     = (const float*)d_in[0];
    const float* Wfc   = (const float*)d_in[1];
    const float* bfc   = (const float*)d_in[2];
    const float* Kc    = (const float*)d_in[3];
    const float* bconv = (const float*)d_in[4];
    const float* W1    = (const float*)d_in[5];
    const float* b1    = (const float*)d_in[6];
    const float* W2    = (const float*)d_in[7];
    const float* b2    = (const float*)d_in[8];
    float* out = (float*)d_out;

    float* concat  = (float*)d_ws;         // [CATN]
    float* partial = concat + CATN;        // [256]

    k_front_v8 <<<FCB2 + (CONVN / 256), 256, 0, stream>>>(
        x, Wfc, bfc, Kc, bconv, concat);
    k_layer1_v2<<<256, 256, 0, stream>>>(W1, concat, partial);
    k_final_v2 <<<1, 128, 0, stream>>>(partial, b1, W2, b2, out);
}

// Round 11
// 76.539 us; speedup vs baseline: 1.2821x; 1.0480x over previous
//
#include <hip/hip_runtime.h>
#include <math.h>

#define CC    144
#define WW    9225
#define KWW   10
#define FF    64
#define H1N   128
#define CONVN (WW - KWW + 1)   // 9216
#define CFN   (CC * FF)        // 9216
#define CATN  (CFN + CONVN)    // 18432
#define FCB2  (CC * 8)         // 1152 fc blocks: (channel c, f-group g of 8)
#define NV4   36               // 36 iters * 64 lanes * 4 floats = 9216
#define NTAIL 9                // 9225 - 9216
#define HOTC  96               // c < HOTC: normal loads (L3-resident slice);
                               // c >= HOTC: nontemporal (no L3 alloc)

typedef float f32x4  __attribute__((ext_vector_type(4)));
typedef float f32x4u __attribute__((ext_vector_type(4), aligned(4)));

// ---------------------------------------------------------------------------
// Stage 1 v9 = v8 (LDS-staged x, 2 rows/wave, HOTC nt split) but the W stream
// is read as lane-consecutive float4 (16B/lane/instr): 4x the bytes per
// outstanding-miss slot vs scalar. Theory: per-CU read BW = inflight_bytes /
// latency; scalar loads starved inflight_bytes. LDS x read as aligned b128.
//   blocks [0, FCB2): fc.  blocks [FCB2, FCB2+36): conv (256 positions each).
// ---------------------------------------------------------------------------
__global__ __launch_bounds__(256) void k_front_v9(
    const float* __restrict__ x,     // [C, W]
    const float* __restrict__ Wfc,   // [C, F, W]
    const float* __restrict__ bfc,   // [C, F]
    const float* __restrict__ Kc,    // [C, KW]
    const float* __restrict__ bconv, // [1]
    float* __restrict__ concat)      // [CATN]
{
    __shared__ float smem[WW];       // 36.9 KB; conv blocks use first 1440
    const int bid = blockIdx.x;
    const int tid = threadIdx.x;

    if (bid < FCB2) {
        const int c = bid >> 3;                   // channel
        const int g = bid & 7;                    // f-group
        const float* __restrict__ xr = x + (size_t)c * WW;

        // ---- stage x row into LDS (coalesced)
        for (int i = tid; i < WW; i += 256) smem[i] = xr[i];
        __syncthreads();

        // ---- each wave: rows r0, r0+1 as float4 streams
        const int wave = tid >> 6;
        const int lane = tid & 63;
        const int f0   = g * 8 + wave * 2;
        const int r0   = (c << 6) + f0;           // fc row index
        const f32x4u* __restrict__ w0v =
            (const f32x4u*)(Wfc + (size_t)r0 * WW);
        const f32x4u* __restrict__ w1v =
            (const f32x4u*)(Wfc + (size_t)(r0 + 1) * WW);
        const f32x4* __restrict__ xv = (const f32x4*)smem;  // 16B-aligned

        float a0 = 0.f, a1 = 0.f;
        if (c < HOTC) {
            #pragma unroll 6
            for (int i = 0; i < NV4; ++i) {
                const int q = i * 64 + lane;      // float4 index, 16B-aligned in x
                const f32x4 xq = xv[q];
                const f32x4 wq0 = w0v[q];
                const f32x4 wq1 = w1v[q];
                a0 += wq0.x * xq.x + wq0.y * xq.y + wq0.z * xq.z + wq0.w * xq.w;
                a1 += wq1.x * xq.x + wq1.y * xq.y + wq1.z * xq.z + wq1.w * xq.w;
            }
        } else {
            #pragma unroll 6
            for (int i = 0; i < NV4; ++i) {
                const int q = i * 64 + lane;
                const f32x4 xq = xv[q];
                const f32x4 wq0 = __builtin_nontemporal_load(w0v + q);
                const f32x4 wq1 = __builtin_nontemporal_load(w1v + q);
                a0 += wq0.x * xq.x + wq0.y * xq.y + wq0.z * xq.z + wq0.w * xq.w;
                a1 += wq1.x * xq.x + wq1.y * xq.y + wq1.z * xq.z + wq1.w * xq.w;
            }
        }
        // tail: elements 9216..9224
        if (lane < NTAIL) {
            const int e = NV4 * 256 + lane;       // 9216 + lane
            const float xq = smem[e];
            const float* __restrict__ wb = Wfc + (size_t)r0 * WW;
            a0 = fmaf(wb[e],      xq, a0);
            a1 = fmaf(wb[WW + e], xq, a1);
        }

        // wave-only reduction — no LDS, no __syncthreads
        #pragma unroll
        for (int off = 32; off > 0; off >>= 1) {
            a0 += __shfl_xor(a0, off, 64);
            a1 += __shfl_xor(a1, off, 64);
        }
        if (lane == 0) {
            concat[r0]     = a0 + bfc[r0];
            concat[r0 + 1] = a1 + bfc[r0 + 1];
        }
    } else {
        // ---- conv: position p = (bid-FCB2)*256 + tid
        for (int i = tid; i < CC * KWW; i += 256) smem[i] = Kc[i];
        __syncthreads();

        const int p = (bid - FCB2) * 256 + tid;   // 36*256 == 9216 exactly
        float acc = bconv[0];
        for (int c = 0; c < CC; ++c) {
            const float* __restrict__ xr = x + (size_t)c * WW + p;
            const float* __restrict__ kr = smem + c * KWW;
            #pragma unroll
            for (int k = 0; k < KWW; ++k)
                acc = fmaf(xr[k], kr[k], acc);
        }
        concat[CFN + p] = acc;
    }
}

// ---------------------------------------------------------------------------
// Stage 2: 256 blocks; block j = (h = j>>1, half = j&1) half-row partial dot.
// ---------------------------------------------------------------------------
__global__ __launch_bounds__(256) void k_layer1_v2(
    const float* __restrict__ W1,     // [H1, CAT]
    const float* __restrict__ concat, // [CAT]
    float* __restrict__ partial)      // [256]
{
    __shared__ float sm[4];
    const int j = blockIdx.x, tid = threadIdx.x;
    const int h = j >> 1, half = j & 1;
    const f32x4* __restrict__ wr =
        (const f32x4*)(W1 + (size_t)h * CATN + half * (CATN / 2));
    const f32x4* __restrict__ cv =
        (const f32x4*)(concat + half * (CATN / 2));

    float acc = 0.f;
    for (int i = tid; i < CATN / 8; i += 256) {   // 9 iters
        const f32x4 a = wr[i];
        const f32x4 q = cv[i];
        acc += a.x * q.x + a.y * q.y + a.z * q.z + a.w * q.w;
    }
    #pragma unroll
    for (int off = 32; off > 0; off >>= 1)
        acc += __shfl_xor(acc, off, 64);
    if ((tid & 63) == 0) sm[tid >> 6] = acc;
    __syncthreads();
    if (tid == 0)
        partial[j] = sm[0] + sm[1] + sm[2] + sm[3];
}

// ---------------------------------------------------------------------------
// Stage 3: combine partials + bias + relu, dot with W2, relu, sigmoid.
// ---------------------------------------------------------------------------
__global__ __launch_bounds__(128) void k_final_v2(
    const float* __restrict__ partial, // [256]
    const float* __restrict__ b1,      // [H1]
    const float* __restrict__ W2,      // [1, H1]
    const float* __restrict__ b2,      // [1]
    float* __restrict__ out)           // [1]
{
    __shared__ float sm[2];
    const int tid = threadIdx.x;
    float v = fmaxf(partial[2 * tid] + partial[2 * tid + 1] + b1[tid], 0.f)
              * W2[tid];
    #pragma unroll
    for (int off = 32; off > 0; off >>= 1)
        v += __shfl_xor(v, off, 64);
    if ((tid & 63) == 0) sm[tid >> 6] = v;
    __syncthreads();
    if (tid == 0) {
        float z = sm[0] + sm[1] + b2[0];
        z = fmaxf(z, 0.f);
        out[0] = 1.f / (1.f + expf(-z));
    }
}

extern "C" void kernel_launch(void* const* d_in, const int* in_sizes, int n_in,
                              void* d_out, int out_size, void* d_ws, size_t ws_size,
                              hipStream_t stream) {
    const float* x     = (const float*)d_in[0];
    const float* Wfc   = (const float*)d_in[1];
    const float* bfc   = (const float*)d_in[2];
    const float* Kc    = (const float*)d_in[3];
    const float* bconv = (const float*)d_in[4];
    const float* W1    = (const float*)d_in[5];
    const float* b1    = (const float*)d_in[6];
    const float* W2    = (const float*)d_in[7];
    const float* b2    = (const float*)d_in[8];
    float* out = (float*)d_out;

    float* concat  = (float*)d_ws;         // [CATN]
    float* partial = concat + CATN;        // [256]

    k_front_v9 <<<FCB2 + (CONVN / 256), 256, 0, stream>>>(
        x, Wfc, bfc, Kc, bconv, concat);
    k_layer1_v2<<<256, 256, 0, stream>>>(W1, concat, partial);
    k_final_v2 <<<1, 128, 0, stream>>>(partial, b1, W2, b2, out);
}